// Round 5
// baseline (329.874 us; speedup 1.0000x reference)
//
#include <hip/hip_runtime.h>
#include <cstdint>
#include <cstddef>

typedef unsigned short u16;
typedef float f32x4 __attribute__((ext_vector_type(4)));
typedef short s16x8 __attribute__((ext_vector_type(8)));

#define DI __device__ __forceinline__

static constexpr int S_  = 2048;
static constexpr int D_  = 2048;
static constexpr int H_  = 16;
static constexpr int HD_ = 128;
static constexpr int HHD = 2048;   // H*HD
static constexpr int CQP = 128;    // CQ=96 padded to 128
static constexpr int NCAT = 640;   // CQP + CKV
static constexpr int CKV_ = 512;
// 1/sqrt(128) * log2(e): softmax done in base-2 (v_exp_f32 is exp2)
static constexpr float QSCALE = 0.12751743360294163f;

DI u16 f2bf(float f) {
  unsigned u = __float_as_uint(f);
  u += 0x7fffu + ((u >> 16) & 1u);   // round-to-nearest-even
  return (u16)(u >> 16);
}
DI float bf2f(u16 h) { return __uint_as_float(((unsigned)h) << 16); }

DI void store_c(float* C, long long i, float v) { C[i] = v; }
DI void store_c(u16* C, long long i, float v) { C[i] = f2bf(v); }

// DPP cross-lane (row of 16) — VALU only, no LDS port
template <int CTRL>
DI float dppf(float x) {
  return __uint_as_float((unsigned)__builtin_amdgcn_mov_dpp(
      (int)__float_as_uint(x), CTRL, 0xf, 0xf, true));
}
DI float red_max16(float x) {
  x = fmaxf(x, dppf<0xB1>(x));
  x = fmaxf(x, dppf<0x4E>(x));
  x = fmaxf(x, dppf<0x141>(x));
  x = fmaxf(x, dppf<0x140>(x));
  return x;
}
DI float red_sum16(float x) {
  x += dppf<0xB1>(x);
  x += dppf<0x4E>(x);
  x += dppf<0x141>(x);
  x += dppf<0x140>(x);
  return x;
}

// async 16B/lane global->LDS; LDS dest is wave-uniform base + lane*16
#define GLD16(g, l)                                                        \
  __builtin_amdgcn_global_load_lds(                                        \
      (__attribute__((address_space(1))) void*)(void*)(const void*)(g),    \
      (__attribute__((address_space(3))) void*)(l), 16, 0, 0)

// ---------------------------------------------------------------------------
// core: C[m][n] = sum_k A[m][k]*B[n][k] (+bias_col[n]) (+bias_row[m])
// double-buffered LDS staging via global_load_lds width-16.
// ---------------------------------------------------------------------------
template <typename OutT, int BCOL, int BROW, int BN>
DI void gemm_core(u16* __restrict__ Asm, u16* __restrict__ Bsm,
                  const u16* __restrict__ A, const u16* __restrict__ B,
                  OutT* __restrict__ C,
                  const float* __restrict__ bias_col,
                  const float* __restrict__ bias_row,
                  int K, int lda, int ldb, int ldc) {
  constexpr int MI = (BN == 128) ? 4 : 2;
  constexpr int NI = 4;
  constexpr int NCH = 8 + BN / 16;   // staging chunks (16 rows x 32 cols each)
  constexpr int NC4 = NCH / 4;
  const int tid  = threadIdx.x;
  const int w    = tid >> 6;
  const int lane = tid & 63;
  const int lr   = lane & 15;
  const int lq   = lane >> 4;
  const long long m0 = (long long)blockIdx.y * 128;
  const long long n0 = (long long)blockIdx.x * BN;
  const int wr = (BN == 128) ? (w >> 1) * 64 : w * 32;
  const int wc = (BN == 128) ? (w & 1) * 64 : 0;

  f32x4 acc[MI][NI];
#pragma unroll
  for (int i = 0; i < MI; ++i)
#pragma unroll
    for (int j = 0; j < NI; ++j)
#pragma unroll
      for (int r = 0; r < 4; ++r) acc[i][j][r] = 0.f;

  const int rch = lane >> 2, cch = (lane & 3) * 8;
  const u16* gsrc[NC4];
  u16* ldst[NC4];
  int bstep[NC4];
#pragma unroll
  for (int ci = 0; ci < NC4; ++ci) {
    const int c = w + ci * 4;
    if (c < 8) {
      gsrc[ci] = A + (m0 + c * 16 + rch) * lda + cch;
      ldst[ci] = &Asm[c * 512];
      bstep[ci] = 128 * 32;
    } else {
      gsrc[ci] = B + (n0 + (c - 8) * 16 + rch) * ldb + cch;
      ldst[ci] = &Bsm[(c - 8) * 512];
      bstep[ci] = BN * 32;
    }
  }
  auto stage = [&](int kt, int b) {
#pragma unroll
    for (int ci = 0; ci < NC4; ++ci) GLD16(gsrc[ci] + kt, ldst[ci] + b * bstep[ci]);
  };

  stage(0, 0);
  int cur = 0;
  for (int kt = 0; kt < K; kt += 32) {
    __syncthreads();
    if (kt + 32 < K) stage(kt + 32, cur ^ 1);
    const u16* Ab = &Asm[cur * 128 * 32];
    const u16* Bb = &Bsm[cur * BN * 32];

    s16x8 af[MI], bfr[NI];
#pragma unroll
    for (int tm = 0; tm < MI; ++tm)
      af[tm] = *(const s16x8*)&Ab[(wr + tm * 16 + lr) * 32 + lq * 8];
#pragma unroll
    for (int tn = 0; tn < NI; ++tn)
      bfr[tn] = *(const s16x8*)&Bb[(wc + tn * 16 + lr) * 32 + lq * 8];
#pragma unroll
    for (int tm = 0; tm < MI; ++tm)
#pragma unroll
      for (int tn = 0; tn < NI; ++tn)
        acc[tm][tn] = __builtin_amdgcn_mfma_f32_16x16x32_bf16(af[tm], bfr[tn],
                                                              acc[tm][tn], 0, 0, 0);
    cur ^= 1;
  }

#pragma unroll
  for (int tm = 0; tm < MI; ++tm)
#pragma unroll
    for (int tn = 0; tn < NI; ++tn) {
      const long long col = n0 + wc + tn * 16 + lr;
      float bc = BCOL ? bias_col[col] : 0.f;
#pragma unroll
      for (int r = 0; r < 4; ++r) {
        const long long row = m0 + wr + tm * 16 + lq * 4 + r;
        float v = acc[tm][tn][r] + bc;
        if (BROW) v += bias_row[row];
        store_c(C, row * (long long)ldc + col, v);
      }
    }
}

template <typename OutT, int BCOL, int BROW, int BN>
__global__ __launch_bounds__(256) void gemm_bt(
    const u16* __restrict__ A, const u16* __restrict__ B, OutT* __restrict__ C,
    const float* __restrict__ bias_col, const float* __restrict__ bias_row,
    int K, int lda, int ldb, int ldc,
    long long sA, long long sB, long long sC) {
  __shared__ __align__(16) u16 As[2 * 128 * 32];
  __shared__ __align__(16) u16 Bs[2 * BN * 32];
  gemm_core<OutT, BCOL, BROW, BN>(
      As, Bs, A + (long long)blockIdx.z * sA, B + (long long)blockIdx.z * sB,
      C + (long long)blockIdx.z * sC, bias_col, bias_row, K, lda, ldb, ldc);
}

// all 3 up-projections in one launch (z selects) -> 768 blocks = 3/CU overlap
__global__ __launch_bounds__(256, 3) void up3(
    const u16* __restrict__ ccat, const u16* __restrict__ wqu,
    const u16* __restrict__ wku, const u16* __restrict__ wvu,
    const float* __restrict__ bq_up, const float* __restrict__ bk_up,
    const float* __restrict__ bv_up,
    u16* __restrict__ qb, u16* __restrict__ kb, u16* __restrict__ vT) {
  __shared__ __align__(16) u16 As[2 * 128 * 32];
  __shared__ __align__(16) u16 Bs[2 * 128 * 32];
  if (blockIdx.z == 0)
    gemm_core<u16, 1, 0, 128>(As, Bs, ccat, wqu, qb, bq_up, nullptr,
                              CQP, NCAT, CQP, HHD);
  else if (blockIdx.z == 1)
    gemm_core<u16, 1, 0, 128>(As, Bs, ccat + CQP, wku, kb, bk_up, nullptr,
                              CKV_, NCAT, CKV_, HHD);
  else  // vT (HHD x S) = wv_up @ c_kv^T (+ bv_up per ROW)
    gemm_core<u16, 0, 1, 128>(As, Bs, wvu, ccat + CQP, vT, nullptr, bv_up,
                              CKV_, CKV_, NCAT, S_);
}

// ---------------------------------------------------------------------------
DI void store4(float* d, long long e, float4 s) { *(float4*)(d + e) = s; }
DI void store4(u16* d, long long e, float4 s) {
  unsigned lo = (unsigned)f2bf(s.x) | ((unsigned)f2bf(s.y) << 16);
  unsigned hi = (unsigned)f2bf(s.z) | ((unsigned)f2bf(s.w) << 16);
  *(uint2*)(d + e) = make_uint2(lo, hi);
}
template <typename OutT>
__global__ __launch_bounds__(256) void combine_z(
    const float* __restrict__ p, long long zs, int nz,
    const float* __restrict__ bias, OutT* __restrict__ dst, int ldc, int n4) {
  int i = blockIdx.x * 256 + threadIdx.x;
  if (i >= n4) return;
  long long e = (long long)i * 4;
  float4 s = *(const float4*)(p + e);
  for (int z = 1; z < nz; ++z) {
    float4 t = *(const float4*)(p + (long long)z * zs + e);
    s.x += t.x; s.y += t.y; s.z += t.z; s.w += t.w;
  }
  int c = (int)(e % ldc);
  s.x += bias[c]; s.y += bias[c + 1]; s.z += bias[c + 2]; s.w += bias[c + 3];
  store4(dst, e, s);
}

// ---------------------------------------------------------------------------
// Flash attention, key-split x2: block = (head, 128-q tile, key-half).
// 4 waves x 32 q-rows (mi=2: each K/V fragment feeds 2 MFMAs -> half LDS
// traffic). LDS = Ks + Vs only (64 KB -> 2 blocks/CU); P reuses Ks buffer.
// Outputs unnormalized O (f32) + per-row (m, l); combine kernel merges.
// ---------------------------------------------------------------------------
__global__ __launch_bounds__(256, 2) void flash_attn(
    const u16* __restrict__ Q, const u16* __restrict__ Kg,
    const u16* __restrict__ Vt, float* __restrict__ Op, float* __restrict__ ml) {
  __shared__ __align__(16) u16 Ks[128 * 128];   // K tile [key][d]; then P tile
  __shared__ __align__(16) u16 Vs[128 * 128];   // V^T tile [d][key]
  const int h = blockIdx.x;
  const int t = blockIdx.y;
  const int kspl = blockIdx.z;
  const int tid = threadIdx.x;
  const int w = tid >> 6, lane = tid & 63, lr = lane & 15, lq = lane >> 4;
  const int qg = t * 128 + w * 32;
  const int tr = tid >> 4;                  // 0..15 staging row
  const int csw = (tid & 15) ^ (tr & 7);    // XOR-swizzled source chunk

  s16x8 qf[2][4];
#pragma unroll
  for (int mi = 0; mi < 2; ++mi)
#pragma unroll
    for (int kst = 0; kst < 4; ++kst)
      qf[mi][kst] = *(const s16x8*)&Q[(size_t)(qg + mi * 16 + lr) * HHD +
                                      h * HD_ + kst * 32 + lq * 8];

  f32x4 oacc[2][8];
  float m[2][4], l[2][4];
#pragma unroll
  for (int mi = 0; mi < 2; ++mi) {
#pragma unroll
    for (int r = 0; r < 4; ++r) { m[mi][r] = -1.0e38f; l[mi][r] = 0.f; }
#pragma unroll
    for (int f = 0; f < 8; ++f)
#pragma unroll
      for (int r = 0; r < 4; ++r) oacc[mi][f][r] = 0.f;
  }

  auto stage_k = [&](int j) {
    const u16* s0 = Kg + (size_t)(j * 128 + tr) * HHD + h * HD_ + csw * 8;
#pragma unroll
    for (int i = 0; i < 8; ++i)
      GLD16(s0 + (size_t)i * 16 * HHD, &Ks[i * 2048 + w * 512]);
  };
  auto stage_v = [&](int j) {
    const u16* s0 = Vt + (size_t)(h * HD_ + tr) * S_ + j * 128 + csw * 8;
#pragma unroll
    for (int i = 0; i < 8; ++i)
      GLD16(s0 + (size_t)i * 16 * S_, &Vs[i * 2048 + w * 512]);
  };

  const int j0 = kspl * 8;
  stage_k(j0);
  stage_v(j0);

  for (int jj = 0; jj < 8; ++jj) {
    __syncthreads();                 // b0: K/V tiles for this j are resident

    // ---- S = Q K^T ----
    f32x4 sacc[2][8];
#pragma unroll
    for (int mi = 0; mi < 2; ++mi)
#pragma unroll
      for (int f = 0; f < 8; ++f)
#pragma unroll
        for (int r = 0; r < 4; ++r) sacc[mi][f][r] = 0.f;
#pragma unroll
    for (int kst = 0; kst < 4; ++kst)
#pragma unroll
      for (int f = 0; f < 8; ++f) {
        s16x8 kf = *(const s16x8*)
            &Ks[(f * 16 + lr) * 128 + (((kst * 4 + lq) ^ (lr & 7)) << 3)];
        sacc[0][f] = __builtin_amdgcn_mfma_f32_16x16x32_bf16(qf[0][kst], kf,
                                                             sacc[0][f], 0, 0, 0);
        sacc[1][f] = __builtin_amdgcn_mfma_f32_16x16x32_bf16(qf[1][kst], kf,
                                                             sacc[1][f], 0, 0, 0);
      }

    // ---- online softmax in base-2 (q pre-scaled by log2e/sqrt(HD)) ----
#pragma unroll
    for (int mi = 0; mi < 2; ++mi)
#pragma unroll
      for (int r = 0; r < 4; ++r) {
        float mx = sacc[mi][0][r];
#pragma unroll
        for (int f = 1; f < 8; ++f) mx = fmaxf(mx, sacc[mi][f][r]);
        mx = red_max16(mx);
        float mn = fmaxf(m[mi][r], mx);
        float al = exp2f(m[mi][r] - mn);
        m[mi][r] = mn;
        float sum = 0.f;
#pragma unroll
        for (int f = 0; f < 8; ++f) {
          float p = exp2f(sacc[mi][f][r] - mn);
          sacc[mi][f][r] = p;
          sum += p;
        }
        sum = red_sum16(sum);
        l[mi][r] = l[mi][r] * al + sum;
#pragma unroll
        for (int f = 0; f < 8; ++f) oacc[mi][f][r] *= al;
      }

    __syncthreads();                 // b1: all waves done reading Ks

    // ---- P -> Ks buffer (bf16, [q][key], XOR-swizzled by q&7) ----
#pragma unroll
    for (int mi = 0; mi < 2; ++mi)
#pragma unroll
      for (int r = 0; r < 4; ++r) {
        const int q = w * 32 + mi * 16 + lq * 4 + r;
#pragma unroll
        for (int f = 0; f < 8; ++f) {
          const int ch = (2 * f + (lr >> 3)) ^ (q & 7);
          Ks[q * 128 + ch * 8 + (lr & 7)] = f2bf(sacc[mi][f][r]);
        }
      }

    __syncthreads();                 // b2: P visible to all waves

    // ---- O += P V ----
#pragma unroll
    for (int kst = 0; kst < 4; ++kst) {
      s16x8 pa0 = *(const s16x8*)
          &Ks[(w * 32 + lr) * 128 + (((kst * 4 + lq) ^ (lr & 7)) << 3)];
      s16x8 pa1 = *(const s16x8*)
          &Ks[(w * 32 + 16 + lr) * 128 + (((kst * 4 + lq) ^ (lr & 7)) << 3)];
#pragma unroll
      for (int f = 0; f < 8; ++f) {
        s16x8 vf = *(const s16x8*)
            &Vs[(f * 16 + lr) * 128 + (((kst * 4 + lq) ^ (lr & 7)) << 3)];
        oacc[0][f] = __builtin_amdgcn_mfma_f32_16x16x32_bf16(pa0, vf,
                                                             oacc[0][f], 0, 0, 0);
        oacc[1][f] = __builtin_amdgcn_mfma_f32_16x16x32_bf16(pa1, vf,
                                                             oacc[1][f], 0, 0, 0);
      }
    }

    __syncthreads();                 // b3: done reading P(Ks) and Vs
    if (jj < 7) {                    // stage next tiles; sibling block computes
      stage_k(j0 + jj + 1);
      stage_v(j0 + jj + 1);
    }
  }

  // ---- epilogue: unnormalized O + (m,l) partials ----
#pragma unroll
  for (int mi = 0; mi < 2; ++mi) {
#pragma unroll
    for (int r = 0; r < 4; ++r) {
      const int row = qg + mi * 16 + lq * 4 + r;
      if (lr == 0) {
        float* p = &ml[((size_t)(kspl * S_ + row) * H_ + h) * 2];
        p[0] = m[mi][r];
        p[1] = l[mi][r];
      }
#pragma unroll
      for (int f = 0; f < 8; ++f)
        Op[(size_t)(kspl * S_ + row) * HHD + h * HD_ + f * 16 + lr] =
            oacc[mi][f][r];
    }
  }
}

__global__ __launch_bounds__(256) void flash_combine(
    const float* __restrict__ Op, const float* __restrict__ ml,
    u16* __restrict__ attnb) {
  int i = blockIdx.x * 256 + threadIdx.x;   // S*HHD/4
  long long e = (long long)i * 4;
  int s = (int)(e >> 11);
  int h = ((int)e & 2047) >> 7;
  const float* p0 = &ml[((size_t)s * H_ + h) * 2];
  const float* p1 = &ml[((size_t)(S_ + s) * H_ + h) * 2];
  float m0 = p0[0], l0 = p0[1], m1 = p1[0], l1 = p1[1];
  float M = fmaxf(m0, m1);
  float w0 = exp2f(m0 - M), w1 = exp2f(m1 - M);
  float inv = 1.f / (w0 * l0 + w1 * l1);
  float4 a = *(const float4*)&Op[e];
  float4 b = *(const float4*)&Op[(size_t)S_ * HHD + e];
  float4 o;
  o.x = (w0 * a.x + w1 * b.x) * inv;
  o.y = (w0 * a.y + w1 * b.y) * inv;
  o.z = (w0 * a.z + w1 * b.z) * inv;
  o.w = (w0 * a.w + w1 * b.w) * inv;
  unsigned lo = (unsigned)f2bf(o.x) | ((unsigned)f2bf(o.y) << 16);
  unsigned hi = (unsigned)f2bf(o.z) | ((unsigned)f2bf(o.w) << 16);
  *(uint2*)(attnb + e) = make_uint2(lo, hi);
}

// ---------------------------------------------------------------------------
// fused prep: all f32->bf16 weight casts/padding + bcat
// ---------------------------------------------------------------------------
DI void cast4(const float* __restrict__ s, u16* __restrict__ d, int v) {
  float4 f = ((const float4*)s)[v];
  unsigned lo = (unsigned)f2bf(f.x) | ((unsigned)f2bf(f.y) << 16);
  unsigned hi = (unsigned)f2bf(f.z) | ((unsigned)f2bf(f.w) << 16);
  ((uint2*)d)[v] = make_uint2(lo, hi);
}
DI void store_bf4(u16* __restrict__ d, long long i, float4 f) {
  unsigned lo = (unsigned)f2bf(f.x) | ((unsigned)f2bf(f.y) << 16);
  unsigned hi = (unsigned)f2bf(f.z) | ((unsigned)f2bf(f.w) << 16);
  *(uint2*)(d + i) = make_uint2(lo, hi);
}
static constexpr int PV_XB   = 1048576;
static constexpr int PV_WCAT = 327680;
static constexpr int PV_WQU  = 65536;
static constexpr int PV_WKU  = 262144;
static constexpr int PV_WVU  = 262144;
static constexpr int PV_WOB  = 1048576;
static constexpr int PV_BCAT = 160;
static constexpr int PV_TOT  = PV_XB + PV_WCAT + PV_WQU + PV_WKU + PV_WVU + PV_WOB + PV_BCAT;

__global__ __launch_bounds__(256) void prep(
    const float* __restrict__ x, const float* __restrict__ wqd_s,
    const float* __restrict__ wkvd_s, const float* __restrict__ wqu_s,
    const float* __restrict__ wku_s, const float* __restrict__ wvu_s,
    const float* __restrict__ wo_s, const float* __restrict__ bqd_s,
    const float* __restrict__ bkvd_s,
    u16* __restrict__ xb, u16* __restrict__ wcat, u16* __restrict__ wqu,
    u16* __restrict__ wku, u16* __restrict__ wvu, u16* __restrict__ wob,
    float* __restrict__ bcat) {
  int v = blockIdx.x * 256 + threadIdx.x;
  if (v >= PV_TOT) return;
  if (v < PV_XB) { cast4(x, xb, v); return; }
  v -= PV_XB;
  if (v < PV_WCAT) {
    int i = v * 4, n = i >> 11, k = i & 2047;
    float4 o = make_float4(0.f, 0.f, 0.f, 0.f);
    if (n < 96)        o = *(const float4*)&wqd_s[n * D_ + k];
    else if (n >= 128) o = *(const float4*)&wkvd_s[(n - 128) * D_ + k];
    store_bf4(wcat, i, o);
    return;
  }
  v -= PV_WCAT;
  if (v < PV_WQU) {
    int i = v * 4, r = i >> 7, c = i & 127;
    float4 o = (c < 96) ? *(const float4*)&wqu_s[r * 96 + c]
                        : make_float4(0.f, 0.f, 0.f, 0.f);
    store_bf4(wqu, i, o);
    return;
  }
  v -= PV_WQU;
  if (v < PV_WKU) { cast4(wku_s, wku, v); return; }
  v -= PV_WKU;
  if (v < PV_WVU) { cast4(wvu_s, wvu, v); return; }
  v -= PV_WVU;
  if (v < PV_WOB) { cast4(wo_s, wob, v); return; }
  v -= PV_WOB;
  {
    int i = v * 4;
    float4 o;
    float* po = &o.x;
#pragma unroll
    for (int jj = 0; jj < 4; ++jj) {
      int e = i + jj;
      po[jj] = (e < 96) ? bqd_s[e] : (e < 128 ? 0.f : bkvd_s[e - 128]);
    }
    *(float4*)&bcat[i] = o;
  }
}

// fused RoPE for q (scaled, incl. log2e fold) and k
__global__ __launch_bounds__(256) void rope2(u16* __restrict__ qb,
                                             u16* __restrict__ kb,
                                             const float* __restrict__ cs,
                                             const float* __restrict__ sn) {
  int id = blockIdx.x * 256 + threadIdx.x;    // 2*S*H*64
  const bool isq = id < S_ * H_ * 64;
  if (!isq) id -= S_ * H_ * 64;
  u16* X = isq ? qb : kb;
  const float scale = isq ? QSCALE : 1.0f;
  int d = id & 63;
  int h = (id >> 6) & 15;
  int s = id >> 10;
  long long b = (long long)s * HHD + h * HD_ + d;
  float x1 = bf2f(X[b]), x2 = bf2f(X[b + 64]);
  int cb = s * HD_ + d;
  float o1 = (x1 * cs[cb] - x2 * sn[cb]) * scale;
  float o2 = (x2 * cs[cb + 64] + x1 * sn[cb + 64]) * scale;
  X[b] = f2bf(o1);
  X[b + 64] = f2bf(o2);
}

// ---------------------------------------------------------------------------
extern "C" void kernel_launch(void* const* d_in, const int* in_sizes, int n_in,
                              void* d_out, int out_size, void* d_ws, size_t ws_size,
                              hipStream_t stream) {
  (void)in_sizes; (void)n_in; (void)out_size; (void)ws_size;
  const float* x        = (const float*)d_in[0];
  const float* rc       = (const float*)d_in[1];
  const float* rs       = (const float*)d_in[2];
  const float* wq_down  = (const float*)d_in[3];
  const float* bq_down  = (const float*)d_in[4];
  const float* wq_up    = (const float*)d_in[5];
  const float* bq_up    = (const float*)d_in[6];
  const float* wkv_down = (const float*)d_in[7];
  const float* bkv_down = (const float*)d_in[8];
  const float* wk_up    = (const float*)d_in[9];
  const float* bk_up    = (const float*)d_in[10];
  const float* wv_up    = (const float*)d_in[11];
  const float* bv_up    = (const float*)d_in[12];
  const float* wo       = (const float*)d_in[13];
  const float* bo       = (const float*)d_in[14];
  float* out = (float*)d_out;

  char* ws = (char*)d_ws;
  size_t off = 0;
  auto alloc = [&](size_t bytes) -> void* {
    off = (off + 255) & ~(size_t)255;
    void* p = ws + off;
    off += bytes;
    return p;
  };

  u16* xb      = (u16*)alloc((size_t)S_ * D_ * 2);
  u16* wcat    = (u16*)alloc((size_t)NCAT * D_ * 2);
  float* bcat  = (float*)alloc(NCAT * 4);
  u16* wqu     = (u16*)alloc((size_t)HHD * CQP * 2);
  u16* wku     = (u16*)alloc((size_t)HHD * CKV_ * 2);
  u16* wvu     = (u16*)alloc((size_t)HHD * CKV_ * 2);
  u16* wob     = (u16*)alloc((size_t)D_ * HHD * 2);
  u16* ccat    = (u16*)alloc((size_t)S_ * NCAT * 2);
  u16* qb      = (u16*)alloc((size_t)S_ * HHD * 2);
  u16* kb      = (u16*)alloc((size_t)S_ * HHD * 2);
  u16* vT      = (u16*)alloc((size_t)HHD * S_ * 2);   // [h*128+d][s]
  u16* attnb   = (u16*)alloc((size_t)S_ * HHD * 2);
  float* Op    = (float*)alloc((size_t)2 * S_ * HHD * 4);   // 32 MB
  float* ml    = (float*)alloc((size_t)2 * S_ * H_ * 2 * 4);
  // pool shared by pcat (21 MB, early) and pout (33.5 MB, late)
  float* pool  = (float*)alloc((size_t)2 * S_ * D_ * 4);
  float* pcat  = pool;
  float* pout  = pool;

  // ---- fused prep ----
  prep<<<(PV_TOT + 255) / 256, 256, 0, stream>>>(
      x, wq_down, wkv_down, wq_up, wk_up, wv_up, wo, bq_down, bkv_down,
      xb, wcat, wqu, wku, wvu, wob, bcat);

  // ---- fused c_q|c_kv projection, split-K x4 ----
  gemm_bt<float, 0, 0, 64><<<dim3(NCAT / 64, 16, 4), 256, 0, stream>>>(
      xb, wcat, pcat, nullptr, nullptr, 512, D_, D_, NCAT,
      512, 512, (long long)S_ * NCAT);
  combine_z<u16><<<(S_ * NCAT / 4 + 255) / 256, 256, 0, stream>>>(
      pcat, (long long)S_ * NCAT, 4, bcat, ccat, NCAT, S_ * NCAT / 4);

  // ---- all three up-projections in one launch (3 blocks/CU) ----
  up3<<<dim3(16, 16, 3), 256, 0, stream>>>(
      ccat, wqu, wku, wvu, bq_up, bk_up, bv_up, qb, kb, vT);

  // ---- RoPE ----
  rope2<<<(2 * S_ * H_ * 64) / 256, 256, 0, stream>>>(qb, kb, rc, rs);

  // ---- flash attention (key-split x2) + combine ----
  flash_attn<<<dim3(H_, S_ / 128, 2), 256, 0, stream>>>(qb, kb, vT, Op, ml);
  flash_combine<<<(S_ * HHD / 4) / 256, 256, 0, stream>>>(Op, ml, attnb);

  // ---- output projection, split-K x2, f32 combine w/ bias ----
  gemm_bt<float, 0, 0, 128><<<dim3(16, 16, 2), 256, 0, stream>>>(
      attnb, wob, pout, nullptr, nullptr, 1024, HHD, HHD, D_,
      1024, 1024, (long long)S_ * D_);
  combine_z<float><<<(S_ * D_ / 4 + 255) / 256, 256, 0, stream>>>(
      pout, (long long)S_ * D_, 2, bo, out, D_, S_ * D_ / 4);
}

// Round 7
// 272.358 us; speedup vs baseline: 1.2112x; 1.2112x over previous
//
#include <hip/hip_runtime.h>
#include <cstdint>
#include <cstddef>

typedef unsigned short u16;
typedef float f32x4 __attribute__((ext_vector_type(4)));
typedef short s16x8 __attribute__((ext_vector_type(8)));

#define DI __device__ __forceinline__

static constexpr int S_  = 2048;
static constexpr int D_  = 2048;
static constexpr int H_  = 16;
static constexpr int HD_ = 128;
static constexpr int HHD = 2048;   // H*HD
static constexpr int CQP = 128;    // CQ=96 padded to 128
static constexpr int NCAT = 640;   // CQP + CKV
static constexpr int CKV_ = 512;
// 1/sqrt(128) * log2(e): softmax done in base-2 (v_exp_f32 is exp2)
static constexpr float QSCALE = 0.12751743360294163f;

DI u16 f2bf(float f) {
  unsigned u = __float_as_uint(f);
  u += 0x7fffu + ((u >> 16) & 1u);   // round-to-nearest-even
  return (u16)(u >> 16);
}
DI float bf2f(u16 h) { return __uint_as_float(((unsigned)h) << 16); }

DI void store_c(float* C, long long i, float v) { C[i] = v; }
DI void store_c(u16* C, long long i, float v) { C[i] = f2bf(v); }

// DPP cross-lane (row of 16) — VALU only, no LDS port
template <int CTRL>
DI float dppf(float x) {
  return __uint_as_float((unsigned)__builtin_amdgcn_mov_dpp(
      (int)__float_as_uint(x), CTRL, 0xf, 0xf, true));
}
DI float red_max16(float x) {
  x = fmaxf(x, dppf<0xB1>(x));
  x = fmaxf(x, dppf<0x4E>(x));
  x = fmaxf(x, dppf<0x141>(x));
  x = fmaxf(x, dppf<0x140>(x));
  return x;
}
DI float red_sum16(float x) {
  x += dppf<0xB1>(x);
  x += dppf<0x4E>(x);
  x += dppf<0x141>(x);
  x += dppf<0x140>(x);
  return x;
}

// async 16B/lane global->LDS; LDS dest is wave-uniform base + lane*16
#define GLD16(g, l)                                                        \
  __builtin_amdgcn_global_load_lds(                                        \
      (__attribute__((address_space(1))) void*)(void*)(const void*)(g),    \
      (__attribute__((address_space(3))) void*)(l), 16, 0, 0)

// ---------------------------------------------------------------------------
// core: C[m][n] = sum_k A[m][k]*B[n][k] (+bias_col[n]) (+bias_row[m])
// double-buffered LDS staging via global_load_lds width-16.
// ---------------------------------------------------------------------------
template <typename OutT, int BCOL, int BROW, int BN>
DI void gemm_core(u16* __restrict__ Asm, u16* __restrict__ Bsm,
                  const u16* __restrict__ A, const u16* __restrict__ B,
                  OutT* __restrict__ C,
                  const float* __restrict__ bias_col,
                  const float* __restrict__ bias_row,
                  int K, int lda, int ldb, int ldc) {
  constexpr int MI = (BN == 128) ? 4 : 2;
  constexpr int NI = 4;
  constexpr int NCH = 8 + BN / 16;   // staging chunks (16 rows x 32 cols each)
  constexpr int NC4 = NCH / 4;
  const int tid  = threadIdx.x;
  const int w    = tid >> 6;
  const int lane = tid & 63;
  const int lr   = lane & 15;
  const int lq   = lane >> 4;
  const long long m0 = (long long)blockIdx.y * 128;
  const long long n0 = (long long)blockIdx.x * BN;
  const int wr = (BN == 128) ? (w >> 1) * 64 : w * 32;
  const int wc = (BN == 128) ? (w & 1) * 64 : 0;

  f32x4 acc[MI][NI];
#pragma unroll
  for (int i = 0; i < MI; ++i)
#pragma unroll
    for (int j = 0; j < NI; ++j)
#pragma unroll
      for (int r = 0; r < 4; ++r) acc[i][j][r] = 0.f;

  const int rch = lane >> 2, cch = (lane & 3) * 8;
  const u16* gsrc[NC4];
  u16* ldst[NC4];
  int bstep[NC4];
#pragma unroll
  for (int ci = 0; ci < NC4; ++ci) {
    const int c = w + ci * 4;
    if (c < 8) {
      gsrc[ci] = A + (m0 + c * 16 + rch) * lda + cch;
      ldst[ci] = &Asm[c * 512];
      bstep[ci] = 128 * 32;
    } else {
      gsrc[ci] = B + (n0 + (c - 8) * 16 + rch) * ldb + cch;
      ldst[ci] = &Bsm[(c - 8) * 512];
      bstep[ci] = BN * 32;
    }
  }
  auto stage = [&](int kt, int b) {
#pragma unroll
    for (int ci = 0; ci < NC4; ++ci) GLD16(gsrc[ci] + kt, ldst[ci] + b * bstep[ci]);
  };

  stage(0, 0);
  int cur = 0;
  for (int kt = 0; kt < K; kt += 32) {
    __syncthreads();
    if (kt + 32 < K) stage(kt + 32, cur ^ 1);
    const u16* Ab = &Asm[cur * 128 * 32];
    const u16* Bb = &Bsm[cur * BN * 32];

    s16x8 af[MI], bfr[NI];
#pragma unroll
    for (int tm = 0; tm < MI; ++tm)
      af[tm] = *(const s16x8*)&Ab[(wr + tm * 16 + lr) * 32 + lq * 8];
#pragma unroll
    for (int tn = 0; tn < NI; ++tn)
      bfr[tn] = *(const s16x8*)&Bb[(wc + tn * 16 + lr) * 32 + lq * 8];
#pragma unroll
    for (int tm = 0; tm < MI; ++tm)
#pragma unroll
      for (int tn = 0; tn < NI; ++tn)
        acc[tm][tn] = __builtin_amdgcn_mfma_f32_16x16x32_bf16(af[tm], bfr[tn],
                                                              acc[tm][tn], 0, 0, 0);
    cur ^= 1;
  }

#pragma unroll
  for (int tm = 0; tm < MI; ++tm)
#pragma unroll
    for (int tn = 0; tn < NI; ++tn) {
      const long long col = n0 + wc + tn * 16 + lr;
      float bc = BCOL ? bias_col[col] : 0.f;
#pragma unroll
      for (int r = 0; r < 4; ++r) {
        const long long row = m0 + wr + tm * 16 + lq * 4 + r;
        float v = acc[tm][tn][r] + bc;
        if (BROW) v += bias_row[row];
        store_c(C, row * (long long)ldc + col, v);
      }
    }
}

template <typename OutT, int BCOL, int BROW, int BN>
__global__ __launch_bounds__(256) void gemm_bt(
    const u16* __restrict__ A, const u16* __restrict__ B, OutT* __restrict__ C,
    const float* __restrict__ bias_col, const float* __restrict__ bias_row,
    int K, int lda, int ldb, int ldc,
    long long sA, long long sB, long long sC) {
  __shared__ __align__(16) u16 As[2 * 128 * 32];
  __shared__ __align__(16) u16 Bs[2 * BN * 32];
  gemm_core<OutT, BCOL, BROW, BN>(
      As, Bs, A + (long long)blockIdx.z * sA, B + (long long)blockIdx.z * sB,
      C + (long long)blockIdx.z * sC, bias_col, bias_row, K, lda, ldb, ldc);
}

// all 3 up-projections in one launch (z selects) -> 768 blocks = 3/CU overlap
__global__ __launch_bounds__(256, 3) void up3(
    const u16* __restrict__ ccat, const u16* __restrict__ wqu,
    const u16* __restrict__ wku, const u16* __restrict__ wvu,
    const float* __restrict__ bq_up, const float* __restrict__ bk_up,
    const float* __restrict__ bv_up,
    u16* __restrict__ qb, u16* __restrict__ kb, u16* __restrict__ vT) {
  __shared__ __align__(16) u16 As[2 * 128 * 32];
  __shared__ __align__(16) u16 Bs[2 * 128 * 32];
  if (blockIdx.z == 0)
    gemm_core<u16, 1, 0, 128>(As, Bs, ccat, wqu, qb, bq_up, nullptr,
                              CQP, NCAT, CQP, HHD);
  else if (blockIdx.z == 1)
    gemm_core<u16, 1, 0, 128>(As, Bs, ccat + CQP, wku, kb, bk_up, nullptr,
                              CKV_, NCAT, CKV_, HHD);
  else  // vT (HHD x S) = wv_up @ c_kv^T (+ bv_up per ROW)
    gemm_core<u16, 0, 1, 128>(As, Bs, wvu, ccat + CQP, vT, nullptr, bv_up,
                              CKV_, CKV_, NCAT, S_);
}

// ---------------------------------------------------------------------------
DI void store4(float* d, long long e, float4 s) { *(float4*)(d + e) = s; }
DI void store4(u16* d, long long e, float4 s) {
  unsigned lo = (unsigned)f2bf(s.x) | ((unsigned)f2bf(s.y) << 16);
  unsigned hi = (unsigned)f2bf(s.z) | ((unsigned)f2bf(s.w) << 16);
  *(uint2*)(d + e) = make_uint2(lo, hi);
}
template <typename OutT>
__global__ __launch_bounds__(256) void combine_z(
    const float* __restrict__ p, long long zs, int nz,
    const float* __restrict__ bias, OutT* __restrict__ dst, int ldc, int n4) {
  int i = blockIdx.x * 256 + threadIdx.x;
  if (i >= n4) return;
  long long e = (long long)i * 4;
  float4 s = *(const float4*)(p + e);
  for (int z = 1; z < nz; ++z) {
    float4 t = *(const float4*)(p + (long long)z * zs + e);
    s.x += t.x; s.y += t.y; s.z += t.z; s.w += t.w;
  }
  int c = (int)(e % ldc);
  s.x += bias[c]; s.y += bias[c + 1]; s.z += bias[c + 2]; s.w += bias[c + 3];
  store4(dst, e, s);
}

// ---------------------------------------------------------------------------
// Flash attention: block = (head, 64-q tile); 4 waves; waves {0,1} handle
// keys 0-63 of each 128-key j-tile, waves {2,3} keys 64-127 (in-block
// key-group split; merged through LDS at epilogue). Each wave mi=2
// (32 q-rows) for fragment reuse. LDS 80 KB -> 2 blocks/CU; grid 512.
// 2 barriers/j: K_{j+1} staged under PV, V_{j+1} under next S-phase.
// ---------------------------------------------------------------------------
__global__ __launch_bounds__(256, 2) void flash_attn(
    const u16* __restrict__ Q, const u16* __restrict__ Kg,
    const u16* __restrict__ Vt, u16* __restrict__ Og) {
  __shared__ __align__(16) u16 Ks[128 * 128];   // [key][d] swizzled; O1 f32 at end
  __shared__ __align__(16) u16 Vs[128 * 128];   // [d][key] swizzled
  __shared__ __align__(16) u16 Ps[64 * 128];    // [q][key] swizzled; m1,l1 at end
  const int h = blockIdx.x;
  const int t = blockIdx.y;
  const int tid = threadIdx.x;
  const int w = tid >> 6, lane = tid & 63, lr = lane & 15, lq = lane >> 4;
  const int g = w >> 1;        // key-group
  const int wq = w & 1;        // q-half within tile
  const int qw = t * 64 + wq * 32;
  const int tr = tid >> 4;
  const int csw = (tid & 15) ^ (tr & 7);   // XOR-swizzled source chunk

  s16x8 qf[2][4];
#pragma unroll
  for (int mi = 0; mi < 2; ++mi)
#pragma unroll
    for (int kst = 0; kst < 4; ++kst)
      qf[mi][kst] = *(const s16x8*)&Q[(size_t)(qw + mi * 16 + lr) * HHD +
                                      h * HD_ + kst * 32 + lq * 8];

  f32x4 oacc[2][8];
  float m[2][4], l[2][4];
#pragma unroll
  for (int mi = 0; mi < 2; ++mi) {
#pragma unroll
    for (int r = 0; r < 4; ++r) { m[mi][r] = -1.0e38f; l[mi][r] = 0.f; }
#pragma unroll
    for (int f = 0; f < 8; ++f)
#pragma unroll
      for (int r = 0; r < 4; ++r) oacc[mi][f][r] = 0.f;
  }

  auto stage_k = [&](int j) {
    const u16* s0 = Kg + (size_t)(j * 128 + tr) * HHD + h * HD_ + csw * 8;
#pragma unroll
    for (int i = 0; i < 8; ++i)
      GLD16(s0 + (size_t)i * 16 * HHD, &Ks[i * 2048 + w * 512]);
  };
  auto stage_v = [&](int j) {
    const u16* s0 = Vt + (size_t)(h * HD_ + tr) * S_ + j * 128 + csw * 8;
#pragma unroll
    for (int i = 0; i < 8; ++i)
      GLD16(s0 + (size_t)i * 16 * S_, &Vs[i * 2048 + w * 512]);
  };

  stage_k(0);
  stage_v(0);
  __syncthreads();                 // K0,V0 resident

  for (int j = 0; j < 16; ++j) {
    // ---- S = Q K^T over this wave's 64-key half ----
    f32x4 sacc[2][4];
#pragma unroll
    for (int mi = 0; mi < 2; ++mi)
#pragma unroll
      for (int f = 0; f < 4; ++f)
#pragma unroll
        for (int r = 0; r < 4; ++r) sacc[mi][f][r] = 0.f;
#pragma unroll
    for (int kst = 0; kst < 4; ++kst)
#pragma unroll
      for (int f = 0; f < 4; ++f) {
        const int key = g * 64 + f * 16 + lr;
        s16x8 kf = *(const s16x8*)
            &Ks[key * 128 + (((kst * 4 + lq) ^ (key & 7)) << 3)];
        sacc[0][f] = __builtin_amdgcn_mfma_f32_16x16x32_bf16(qf[0][kst], kf,
                                                             sacc[0][f], 0, 0, 0);
        sacc[1][f] = __builtin_amdgcn_mfma_f32_16x16x32_bf16(qf[1][kst], kf,
                                                             sacc[1][f], 0, 0, 0);
      }

    // ---- online softmax in base-2 (per key-group partial) ----
#pragma unroll
    for (int mi = 0; mi < 2; ++mi)
#pragma unroll
      for (int r = 0; r < 4; ++r) {
        float mx = sacc[mi][0][r];
#pragma unroll
        for (int f = 1; f < 4; ++f) mx = fmaxf(mx, sacc[mi][f][r]);
        mx = red_max16(mx);
        float mn = fmaxf(m[mi][r], mx);
        float al = exp2f(m[mi][r] - mn);
        m[mi][r] = mn;
        float sum = 0.f;
#pragma unroll
        for (int f = 0; f < 4; ++f) {
          float p = exp2f(sacc[mi][f][r] - mn);
          sacc[mi][f][r] = p;
          sum += p;
        }
        sum = red_sum16(sum);
        l[mi][r] = l[mi][r] * al + sum;
#pragma unroll
        for (int f = 0; f < 8; ++f) oacc[mi][f][r] *= al;
      }

    // ---- P -> Ps (bf16, [q 0..63][key 0..127], chunk ^= q&7) ----
#pragma unroll
    for (int mi = 0; mi < 2; ++mi)
#pragma unroll
      for (int r = 0; r < 4; ++r) {
        const int q = wq * 32 + mi * 16 + lq * 4 + r;
#pragma unroll
        for (int f = 0; f < 4; ++f) {
          const int ch = (g * 8 + f * 2 + (lr >> 3)) ^ (q & 7);
          Ps[q * 128 + ch * 8 + (lr & 7)] = f2bf(sacc[mi][f][r]);
        }
      }

    __syncthreads();               // Ks consumed; P visible; V_j drained
    if (j < 15) stage_k(j + 1);    // overlaps PV

    // ---- O += P V over this wave's 64-key half ----
#pragma unroll
    for (int kst = 0; kst < 2; ++kst) {
      const int chA = (g * 8 + kst * 4 + lq) ^ (lr & 7);
      s16x8 pa0 = *(const s16x8*)&Ps[(wq * 32 + lr) * 128 + chA * 8];
      s16x8 pa1 = *(const s16x8*)&Ps[(wq * 32 + 16 + lr) * 128 + chA * 8];
#pragma unroll
      for (int f = 0; f < 8; ++f) {
        const int d = f * 16 + lr;
        s16x8 vf = *(const s16x8*)
            &Vs[d * 128 + (((g * 8 + kst * 4 + lq) ^ (d & 7)) << 3)];
        oacc[0][f] = __builtin_amdgcn_mfma_f32_16x16x32_bf16(pa0, vf,
                                                             oacc[0][f], 0, 0, 0);
        oacc[1][f] = __builtin_amdgcn_mfma_f32_16x16x32_bf16(pa1, vf,
                                                             oacc[1][f], 0, 0, 0);
      }
    }

    __syncthreads();               // Vs + Ps consumed; K_{j+1} drained
    if (j < 15) stage_v(j + 1);    // overlaps next S-phase
  }

  // ---- epilogue: merge the two key-groups through LDS ----
  float* KsF = (float*)Ks;         // O1: [q 0..63][d 0..127] f32 (32 KB)
  float* mlF = (float*)Ps;         // m1,l1: [q 0..63][2]
  if (g == 1) {
#pragma unroll
    for (int mi = 0; mi < 2; ++mi)
#pragma unroll
      for (int r = 0; r < 4; ++r) {
        const int q = wq * 32 + mi * 16 + lq * 4 + r;
        if (lr == 0) { mlF[q * 2] = m[mi][r]; mlF[q * 2 + 1] = l[mi][r]; }
#pragma unroll
        for (int f = 0; f < 8; ++f)
          KsF[q * 128 + f * 16 + lr] = oacc[mi][f][r];
      }
  }
  __syncthreads();
  if (g == 0) {
#pragma unroll
    for (int mi = 0; mi < 2; ++mi)
#pragma unroll
      for (int r = 0; r < 4; ++r) {
        const int q = wq * 32 + mi * 16 + lq * 4 + r;
        float m1 = mlF[q * 2], l1 = mlF[q * 2 + 1];
        float M = fmaxf(m[mi][r], m1);
        float w0 = exp2f(m[mi][r] - M), w1 = exp2f(m1 - M);
        float inv = 1.f / (w0 * l[mi][r] + w1 * l1);
        w0 *= inv; w1 *= inv;
#pragma unroll
        for (int f = 0; f < 8; ++f) {
          float o = w0 * oacc[mi][f][r] + w1 * KsF[q * 128 + f * 16 + lr];
          Og[(size_t)(t * 64 + q) * HHD + h * HD_ + f * 16 + lr] = f2bf(o);
        }
      }
  }
}

// ---------------------------------------------------------------------------
// fused prep: all f32->bf16 weight casts/padding + bcat
// ---------------------------------------------------------------------------
DI void cast4(const float* __restrict__ s, u16* __restrict__ d, int v) {
  float4 f = ((const float4*)s)[v];
  unsigned lo = (unsigned)f2bf(f.x) | ((unsigned)f2bf(f.y) << 16);
  unsigned hi = (unsigned)f2bf(f.z) | ((unsigned)f2bf(f.w) << 16);
  ((uint2*)d)[v] = make_uint2(lo, hi);
}
DI void store_bf4(u16* __restrict__ d, long long i, float4 f) {
  unsigned lo = (unsigned)f2bf(f.x) | ((unsigned)f2bf(f.y) << 16);
  unsigned hi = (unsigned)f2bf(f.z) | ((unsigned)f2bf(f.w) << 16);
  *(uint2*)(d + i) = make_uint2(lo, hi);
}
static constexpr int PV_XB   = 1048576;
static constexpr int PV_WCAT = 327680;
static constexpr int PV_WQU  = 65536;
static constexpr int PV_WKU  = 262144;
static constexpr int PV_WVU  = 262144;
static constexpr int PV_WOB  = 1048576;
static constexpr int PV_BCAT = 160;
static constexpr int PV_TOT  = PV_XB + PV_WCAT + PV_WQU + PV_WKU + PV_WVU + PV_WOB + PV_BCAT;

__global__ __launch_bounds__(256) void prep(
    const float* __restrict__ x, const float* __restrict__ wqd_s,
    const float* __restrict__ wkvd_s, const float* __restrict__ wqu_s,
    const float* __restrict__ wku_s, const float* __restrict__ wvu_s,
    const float* __restrict__ wo_s, const float* __restrict__ bqd_s,
    const float* __restrict__ bkvd_s,
    u16* __restrict__ xb, u16* __restrict__ wcat, u16* __restrict__ wqu,
    u16* __restrict__ wku, u16* __restrict__ wvu, u16* __restrict__ wob,
    float* __restrict__ bcat) {
  int v = blockIdx.x * 256 + threadIdx.x;
  if (v >= PV_TOT) return;
  if (v < PV_XB) { cast4(x, xb, v); return; }
  v -= PV_XB;
  if (v < PV_WCAT) {
    int i = v * 4, n = i >> 11, k = i & 2047;
    float4 o = make_float4(0.f, 0.f, 0.f, 0.f);
    if (n < 96)        o = *(const float4*)&wqd_s[n * D_ + k];
    else if (n >= 128) o = *(const float4*)&wkvd_s[(n - 128) * D_ + k];
    store_bf4(wcat, i, o);
    return;
  }
  v -= PV_WCAT;
  if (v < PV_WQU) {
    int i = v * 4, r = i >> 7, c = i & 127;
    float4 o = (c < 96) ? *(const float4*)&wqu_s[r * 96 + c]
                        : make_float4(0.f, 0.f, 0.f, 0.f);
    store_bf4(wqu, i, o);
    return;
  }
  v -= PV_WQU;
  if (v < PV_WKU) { cast4(wku_s, wku, v); return; }
  v -= PV_WKU;
  if (v < PV_WVU) { cast4(wvu_s, wvu, v); return; }
  v -= PV_WVU;
  if (v < PV_WOB) { cast4(wo_s, wob, v); return; }
  v -= PV_WOB;
  {
    int i = v * 4;
    float4 o;
    float* po = &o.x;
#pragma unroll
    for (int jj = 0; jj < 4; ++jj) {
      int e = i + jj;
      po[jj] = (e < 96) ? bqd_s[e] : (e < 128 ? 0.f : bkvd_s[e - 128]);
    }
    *(float4*)&bcat[i] = o;
  }
}

// fused RoPE for q (scaled, incl. log2e fold) and k
__global__ __launch_bounds__(256) void rope2(u16* __restrict__ qb,
                                             u16* __restrict__ kb,
                                             const float* __restrict__ cs,
                                             const float* __restrict__ sn) {
  int id = blockIdx.x * 256 + threadIdx.x;    // 2*S*H*64
  const bool isq = id < S_ * H_ * 64;
  if (!isq) id -= S_ * H_ * 64;
  u16* X = isq ? qb : kb;
  const float scale = isq ? QSCALE : 1.0f;
  int d = id & 63;
  int h = (id >> 6) & 15;
  int s = id >> 10;
  long long b = (long long)s * HHD + h * HD_ + d;
  float x1 = bf2f(X[b]), x2 = bf2f(X[b + 64]);
  int cb = s * HD_ + d;
  float o1 = (x1 * cs[cb] - x2 * sn[cb]) * scale;
  float o2 = (x2 * cs[cb + 64] + x1 * sn[cb + 64]) * scale;
  X[b] = f2bf(o1);
  X[b + 64] = f2bf(o2);
}

// ---------------------------------------------------------------------------
extern "C" void kernel_launch(void* const* d_in, const int* in_sizes, int n_in,
                              void* d_out, int out_size, void* d_ws, size_t ws_size,
                              hipStream_t stream) {
  (void)in_sizes; (void)n_in; (void)out_size; (void)ws_size;
  const float* x        = (const float*)d_in[0];
  const float* rc       = (const float*)d_in[1];
  const float* rs       = (const float*)d_in[2];
  const float* wq_down  = (const float*)d_in[3];
  const float* bq_down  = (const float*)d_in[4];
  const float* wq_up    = (const float*)d_in[5];
  const float* bq_up    = (const float*)d_in[6];
  const float* wkv_down = (const float*)d_in[7];
  const float* bkv_down = (const float*)d_in[8];
  const float* wk_up    = (const float*)d_in[9];
  const float* bk_up    = (const float*)d_in[10];
  const float* wv_up    = (const float*)d_in[11];
  const float* bv_up    = (const float*)d_in[12];
  const float* wo       = (const float*)d_in[13];
  const float* bo       = (const float*)d_in[14];
  float* out = (float*)d_out;

  char* ws = (char*)d_ws;
  size_t off = 0;
  auto alloc = [&](size_t bytes) -> void* {
    off = (off + 255) & ~(size_t)255;
    void* p = ws + off;
    off += bytes;
    return p;
  };

  u16* xb      = (u16*)alloc((size_t)S_ * D_ * 2);
  u16* wcat    = (u16*)alloc((size_t)NCAT * D_ * 2);
  float* bcat  = (float*)alloc(NCAT * 4);
  u16* wqu     = (u16*)alloc((size_t)HHD * CQP * 2);
  u16* wku     = (u16*)alloc((size_t)HHD * CKV_ * 2);
  u16* wvu     = (u16*)alloc((size_t)HHD * CKV_ * 2);
  u16* wob     = (u16*)alloc((size_t)D_ * HHD * 2);
  u16* ccat    = (u16*)alloc((size_t)S_ * NCAT * 2);
  u16* qb      = (u16*)alloc((size_t)S_ * HHD * 2);
  u16* kb      = (u16*)alloc((size_t)S_ * HHD * 2);
  u16* vT      = (u16*)alloc((size_t)HHD * S_ * 2);   // [h*128+d][s]
  u16* attnb   = (u16*)alloc((size_t)S_ * HHD * 2);
  // pool shared by pcat (21 MB, early) and pout (33.5 MB, late)
  float* pool  = (float*)alloc((size_t)2 * S_ * D_ * 4);
  float* pcat  = pool;
  float* pout  = pool;

  // ---- fused prep ----
  prep<<<(PV_TOT + 255) / 256, 256, 0, stream>>>(
      x, wq_down, wkv_down, wq_up, wk_up, wv_up, wo, bq_down, bkv_down,
      xb, wcat, wqu, wku, wvu, wob, bcat);

  // ---- fused c_q|c_kv projection, split-K x4 ----
  gemm_bt<float, 0, 0, 64><<<dim3(NCAT / 64, 16, 4), 256, 0, stream>>>(
      xb, wcat, pcat, nullptr, nullptr, 512, D_, D_, NCAT,
      512, 512, (long long)S_ * NCAT);
  combine_z<u16><<<(S_ * NCAT / 4 + 255) / 256, 256, 0, stream>>>(
      pcat, (long long)S_ * NCAT, 4, bcat, ccat, NCAT, S_ * NCAT / 4);

  // ---- all three up-projections in one launch (3 blocks/CU) ----
  up3<<<dim3(16, 16, 3), 256, 0, stream>>>(
      ccat, wqu, wku, wvu, bq_up, bk_up, bv_up, qb, kb, vT);

  // ---- RoPE ----
  rope2<<<(2 * S_ * H_ * 64) / 256, 256, 0, stream>>>(qb, kb, rc, rs);

  // ---- fused flash attention (q-tile 64, 512 blocks = 2/CU) ----
  flash_attn<<<dim3(H_, S_ / 64, 1), 256, 0, stream>>>(qb, kb, vT, attnb);

  // ---- output projection, split-K x2, f32 combine w/ bias ----
  gemm_bt<float, 0, 0, 128><<<dim3(16, 16, 2), 256, 0, stream>>>(
      attnb, wob, pout, nullptr, nullptr, 1024, HHD, HHD, D_,
      1024, 1024, (long long)S_ * D_);
  combine_z<float><<<(S_ * D_ / 4 + 255) / 256, 256, 0, stream>>>(
      pout, (long long)S_ * D_, 2, bo, out, D_, S_ * D_ / 4);
}

// Round 8
// 268.483 us; speedup vs baseline: 1.2287x; 1.0144x over previous
//
#include <hip/hip_runtime.h>
#include <cstdint>
#include <cstddef>

typedef unsigned short u16;
typedef float f32x4 __attribute__((ext_vector_type(4)));
typedef short s16x8 __attribute__((ext_vector_type(8)));

#define DI __device__ __forceinline__

static constexpr int S_  = 2048;
static constexpr int D_  = 2048;
static constexpr int H_  = 16;
static constexpr int HD_ = 128;
static constexpr int HHD = 2048;   // H*HD
static constexpr int CQP = 128;    // CQ=96 padded to 128
static constexpr int NCAT = 640;   // CQP + CKV
static constexpr int CKV_ = 512;
// 1/sqrt(128) * log2(e): softmax done in base-2 (v_exp_f32 is exp2)
static constexpr float QSCALE = 0.12751743360294163f;

DI u16 f2bf(float f) {
  unsigned u = __float_as_uint(f);
  u += 0x7fffu + ((u >> 16) & 1u);   // round-to-nearest-even
  return (u16)(u >> 16);
}
DI float bf2f(u16 h) { return __uint_as_float(((unsigned)h) << 16); }

DI void store_c(float* C, long long i, float v) { C[i] = v; }
DI void store_c(u16* C, long long i, float v) { C[i] = f2bf(v); }

// DPP cross-lane (row of 16) — VALU only, no LDS port
template <int CTRL>
DI float dppf(float x) {
  return __uint_as_float((unsigned)__builtin_amdgcn_mov_dpp(
      (int)__float_as_uint(x), CTRL, 0xf, 0xf, true));
}
DI float red_max16(float x) {
  x = fmaxf(x, dppf<0xB1>(x));
  x = fmaxf(x, dppf<0x4E>(x));
  x = fmaxf(x, dppf<0x141>(x));
  x = fmaxf(x, dppf<0x140>(x));
  return x;
}
DI float red_sum16(float x) {
  x += dppf<0xB1>(x);
  x += dppf<0x4E>(x);
  x += dppf<0x141>(x);
  x += dppf<0x140>(x);
  return x;
}

// async 16B/lane global->LDS; LDS dest is wave-uniform base + lane*16
#define GLD16(g, l)                                                        \
  __builtin_amdgcn_global_load_lds(                                        \
      (__attribute__((address_space(1))) void*)(void*)(const void*)(g),    \
      (__attribute__((address_space(3))) void*)(l), 16, 0, 0)

// ---------------------------------------------------------------------------
// core: C[m][n] = sum_k A[m][k]*B[n][k] (+bias_col[n]) (+bias_row[m])
// double-buffered LDS staging via global_load_lds width-16.
// ROPE=1 (BN=128, OutT=u16): wave holds (d, d+64) column pairs; epilogue
// applies bias -> rope (cos/sin halves identical) -> *scale -> bf16 store.
// ---------------------------------------------------------------------------
template <typename OutT, int BCOL, int BROW, int ROPE, int BN>
DI void gemm_core(u16* __restrict__ Asm, u16* __restrict__ Bsm,
                  const u16* __restrict__ A, const u16* __restrict__ B,
                  OutT* __restrict__ C,
                  const float* __restrict__ bias_col,
                  const float* __restrict__ bias_row,
                  int K, int lda, int ldb, int ldc,
                  const float* __restrict__ rcs, const float* __restrict__ rsn,
                  float scale) {
  constexpr int MI = (BN == 128) ? 4 : 2;
  constexpr int NI = 4;
  constexpr int NCH = 8 + BN / 16;   // staging chunks (16 rows x 32 cols each)
  constexpr int NC4 = NCH / 4;
  const int tid  = threadIdx.x;
  const int w    = tid >> 6;
  const int lane = tid & 63;
  const int lr   = lane & 15;
  const int lq   = lane >> 4;
  const long long m0 = (long long)blockIdx.y * 128;
  const long long n0 = (long long)blockIdx.x * BN;
  const int wr = (BN == 128) ? (w >> 1) * 64 : w * 32;
  const int wc = (BN == 128) ? (w & 1) * 64 : 0;

  f32x4 acc[MI][NI];
#pragma unroll
  for (int i = 0; i < MI; ++i)
#pragma unroll
    for (int j = 0; j < NI; ++j)
#pragma unroll
      for (int r = 0; r < 4; ++r) acc[i][j][r] = 0.f;

  const int rch = lane >> 2, cch = (lane & 3) * 8;
  const u16* gsrc[NC4];
  u16* ldst[NC4];
  int bstep[NC4];
#pragma unroll
  for (int ci = 0; ci < NC4; ++ci) {
    const int c = w + ci * 4;
    if (c < 8) {
      gsrc[ci] = A + (m0 + c * 16 + rch) * lda + cch;
      ldst[ci] = &Asm[c * 512];
      bstep[ci] = 128 * 32;
    } else {
      gsrc[ci] = B + (n0 + (c - 8) * 16 + rch) * ldb + cch;
      ldst[ci] = &Bsm[(c - 8) * 512];
      bstep[ci] = BN * 32;
    }
  }
  auto stage = [&](int kt, int b) {
#pragma unroll
    for (int ci = 0; ci < NC4; ++ci) GLD16(gsrc[ci] + kt, ldst[ci] + b * bstep[ci]);
  };

  stage(0, 0);
  int cur = 0;
  for (int kt = 0; kt < K; kt += 32) {
    __syncthreads();
    if (kt + 32 < K) stage(kt + 32, cur ^ 1);
    const u16* Ab = &Asm[cur * 128 * 32];
    const u16* Bb = &Bsm[cur * BN * 32];

    s16x8 af[MI], bfr[NI];
#pragma unroll
    for (int tm = 0; tm < MI; ++tm)
      af[tm] = *(const s16x8*)&Ab[(wr + tm * 16 + lr) * 32 + lq * 8];
#pragma unroll
    for (int tn = 0; tn < NI; ++tn) {
      const int cb = ROPE ? ((w & 1) * 32 + (tn & 1) * 16 + (tn >> 1) * 64)
                          : (wc + tn * 16);
      bfr[tn] = *(const s16x8*)&Bb[(cb + lr) * 32 + lq * 8];
    }
#pragma unroll
    for (int tm = 0; tm < MI; ++tm)
#pragma unroll
      for (int tn = 0; tn < NI; ++tn)
        acc[tm][tn] = __builtin_amdgcn_mfma_f32_16x16x32_bf16(af[tm], bfr[tn],
                                                              acc[tm][tn], 0, 0, 0);
    cur ^= 1;
  }

  if (ROPE) {
#pragma unroll
    for (int tm = 0; tm < MI; ++tm)
#pragma unroll
      for (int tn = 0; tn < 2; ++tn) {
        const long long col1 = n0 + (w & 1) * 32 + tn * 16 + lr;
        const long long col2 = col1 + 64;
        const float bc1 = bias_col[col1];
        const float bc2 = bias_col[col2];
        const int dd = (int)(col1 & 127);   // < 64
#pragma unroll
        for (int r = 0; r < 4; ++r) {
          const long long row = m0 + wr + tm * 16 + lq * 4 + r;
          const float c = rcs[row * 128 + dd];
          const float s = rsn[row * 128 + dd];
          const float v1 = acc[tm][tn][r] + bc1;
          const float v2 = acc[tm][tn + 2][r] + bc2;
          store_c(C, row * (long long)ldc + col1, (v1 * c - v2 * s) * scale);
          store_c(C, row * (long long)ldc + col2, (v2 * c + v1 * s) * scale);
        }
      }
  } else {
#pragma unroll
    for (int tm = 0; tm < MI; ++tm)
#pragma unroll
      for (int tn = 0; tn < NI; ++tn) {
        const long long col = n0 + wc + tn * 16 + lr;
        float bc = BCOL ? bias_col[col] : 0.f;
#pragma unroll
        for (int r = 0; r < 4; ++r) {
          const long long row = m0 + wr + tm * 16 + lq * 4 + r;
          float v = acc[tm][tn][r] + bc;
          if (BROW) v += bias_row[row];
          store_c(C, row * (long long)ldc + col, v);
        }
      }
  }
}

template <typename OutT, int BCOL, int BROW, int BN>
__global__ __launch_bounds__(256) void gemm_bt(
    const u16* __restrict__ A, const u16* __restrict__ B, OutT* __restrict__ C,
    const float* __restrict__ bias_col, const float* __restrict__ bias_row,
    int K, int lda, int ldb, int ldc,
    long long sA, long long sB, long long sC) {
  __shared__ __align__(16) u16 As[2 * 128 * 32];
  __shared__ __align__(16) u16 Bs[2 * BN * 32];
  gemm_core<OutT, BCOL, BROW, 0, BN>(
      As, Bs, A + (long long)blockIdx.z * sA, B + (long long)blockIdx.z * sB,
      C + (long long)blockIdx.z * sC, bias_col, bias_row, K, lda, ldb, ldc,
      nullptr, nullptr, 0.f);
}

// all 3 up-projections in one launch (z selects); q/k get fused RoPE.
__global__ __launch_bounds__(256, 3) void up3(
    const u16* __restrict__ ccat, const u16* __restrict__ wqu,
    const u16* __restrict__ wku, const u16* __restrict__ wvu,
    const float* __restrict__ bq_up, const float* __restrict__ bk_up,
    const float* __restrict__ bv_up,
    const float* __restrict__ rcs, const float* __restrict__ rsn,
    u16* __restrict__ qb, u16* __restrict__ kb, u16* __restrict__ vT) {
  __shared__ __align__(16) u16 As[2 * 128 * 32];
  __shared__ __align__(16) u16 Bs[2 * 128 * 32];
  if (blockIdx.z == 0)
    gemm_core<u16, 1, 0, 1, 128>(As, Bs, ccat, wqu, qb, bq_up, nullptr,
                                 CQP, NCAT, CQP, HHD, rcs, rsn, QSCALE);
  else if (blockIdx.z == 1)
    gemm_core<u16, 1, 0, 1, 128>(As, Bs, ccat + CQP, wku, kb, bk_up, nullptr,
                                 CKV_, NCAT, CKV_, HHD, rcs, rsn, 1.0f);
  else  // vT (HHD x S) = wv_up @ c_kv^T (+ bv_up per ROW)
    gemm_core<u16, 0, 1, 0, 128>(As, Bs, wvu, ccat + CQP, vT, nullptr, bv_up,
                                 CKV_, CKV_, NCAT, S_, nullptr, nullptr, 0.f);
}

// ---------------------------------------------------------------------------
DI void store4(float* d, long long e, float4 s) { *(float4*)(d + e) = s; }
DI void store4(u16* d, long long e, float4 s) {
  unsigned lo = (unsigned)f2bf(s.x) | ((unsigned)f2bf(s.y) << 16);
  unsigned hi = (unsigned)f2bf(s.z) | ((unsigned)f2bf(s.w) << 16);
  *(uint2*)(d + e) = make_uint2(lo, hi);
}
template <typename OutT>
__global__ __launch_bounds__(256) void combine_z(
    const float* __restrict__ p, long long zs, int nz,
    const float* __restrict__ bias, OutT* __restrict__ dst, int ldc, int n4) {
  int i = blockIdx.x * 256 + threadIdx.x;
  if (i >= n4) return;
  long long e = (long long)i * 4;
  float4 s = *(const float4*)(p + e);
  for (int z = 1; z < nz; ++z) {
    float4 t = *(const float4*)(p + (long long)z * zs + e);
    s.x += t.x; s.y += t.y; s.z += t.z; s.w += t.w;
  }
  int c = (int)(e % ldc);
  s.x += bias[c]; s.y += bias[c + 1]; s.z += bias[c + 2]; s.w += bias[c + 3];
  store4(dst, e, s);
}

// ---------------------------------------------------------------------------
// Flash attention: block = (head, 64-q tile); 4 waves; waves {0,1} handle
// keys 0-63 of each 128-key j-tile, waves {2,3} keys 64-127 (in-block
// key-group split; merged through LDS at epilogue). mi=2 per wave.
// l kept as per-lane partial (reduced once at end); rescale skipped via
// wave-uniform __any when the running max didn't grow.
// ---------------------------------------------------------------------------
__global__ __launch_bounds__(256, 2) void flash_attn(
    const u16* __restrict__ Q, const u16* __restrict__ Kg,
    const u16* __restrict__ Vt, u16* __restrict__ Og) {
  __shared__ __align__(16) u16 Ks[128 * 128];   // [key][d] swizzled; O1 f32 at end
  __shared__ __align__(16) u16 Vs[128 * 128];   // [d][key] swizzled
  __shared__ __align__(16) u16 Ps[64 * 128];    // [q][key] swizzled; m1,l1 at end
  const int h = blockIdx.x;
  const int t = blockIdx.y;
  const int tid = threadIdx.x;
  const int w = tid >> 6, lane = tid & 63, lr = lane & 15, lq = lane >> 4;
  const int g = w >> 1;        // key-group
  const int wq = w & 1;        // q-half within tile
  const int qw = t * 64 + wq * 32;
  const int tr = tid >> 4;
  const int csw = (tid & 15) ^ (tr & 7);   // XOR-swizzled source chunk

  s16x8 qf[2][4];
#pragma unroll
  for (int mi = 0; mi < 2; ++mi)
#pragma unroll
    for (int kst = 0; kst < 4; ++kst)
      qf[mi][kst] = *(const s16x8*)&Q[(size_t)(qw + mi * 16 + lr) * HHD +
                                      h * HD_ + kst * 32 + lq * 8];

  f32x4 oacc[2][8];
  float m[2][4], l[2][4];   // l: per-LANE partial (sum over own cols)
#pragma unroll
  for (int mi = 0; mi < 2; ++mi) {
#pragma unroll
    for (int r = 0; r < 4; ++r) { m[mi][r] = -1.0e38f; l[mi][r] = 0.f; }
#pragma unroll
    for (int f = 0; f < 8; ++f)
#pragma unroll
      for (int r = 0; r < 4; ++r) oacc[mi][f][r] = 0.f;
  }

  auto stage_k = [&](int j) {
    const u16* s0 = Kg + (size_t)(j * 128 + tr) * HHD + h * HD_ + csw * 8;
#pragma unroll
    for (int i = 0; i < 8; ++i)
      GLD16(s0 + (size_t)i * 16 * HHD, &Ks[i * 2048 + w * 512]);
  };
  auto stage_v = [&](int j) {
    const u16* s0 = Vt + (size_t)(h * HD_ + tr) * S_ + j * 128 + csw * 8;
#pragma unroll
    for (int i = 0; i < 8; ++i)
      GLD16(s0 + (size_t)i * 16 * S_, &Vs[i * 2048 + w * 512]);
  };

  stage_k(0);
  stage_v(0);
  __syncthreads();                 // K0,V0 resident

  for (int j = 0; j < 16; ++j) {
    // ---- S = Q K^T over this wave's 64-key half ----
    f32x4 sacc[2][4];
#pragma unroll
    for (int mi = 0; mi < 2; ++mi)
#pragma unroll
      for (int f = 0; f < 4; ++f)
#pragma unroll
        for (int r = 0; r < 4; ++r) sacc[mi][f][r] = 0.f;
#pragma unroll
    for (int kst = 0; kst < 4; ++kst)
#pragma unroll
      for (int f = 0; f < 4; ++f) {
        const int key = g * 64 + f * 16 + lr;
        s16x8 kf = *(const s16x8*)
            &Ks[key * 128 + (((kst * 4 + lq) ^ (key & 7)) << 3)];
        sacc[0][f] = __builtin_amdgcn_mfma_f32_16x16x32_bf16(qf[0][kst], kf,
                                                             sacc[0][f], 0, 0, 0);
        sacc[1][f] = __builtin_amdgcn_mfma_f32_16x16x32_bf16(qf[1][kst], kf,
                                                             sacc[1][f], 0, 0, 0);
      }

    // ---- online softmax in base-2 ----
#pragma unroll
    for (int mi = 0; mi < 2; ++mi) {
      float mx[4];
      bool need = false;
#pragma unroll
      for (int r = 0; r < 4; ++r) {
        float v = sacc[mi][0][r];
#pragma unroll
        for (int f = 1; f < 4; ++f) v = fmaxf(v, sacc[mi][f][r]);
        mx[r] = red_max16(v);
        need = need || (mx[r] > m[mi][r]);
      }
      if (__any(need)) {           // wave-uniform; skipped when max stable
#pragma unroll
        for (int r = 0; r < 4; ++r) {
          float mn = fmaxf(m[mi][r], mx[r]);
          float al = exp2f(m[mi][r] - mn);
          m[mi][r] = mn;
          l[mi][r] *= al;
#pragma unroll
          for (int f = 0; f < 8; ++f) oacc[mi][f][r] *= al;
        }
      }
#pragma unroll
      for (int r = 0; r < 4; ++r) {
        float sum = 0.f;
#pragma unroll
        for (int f = 0; f < 4; ++f) {
          float p = exp2f(sacc[mi][f][r] - m[mi][r]);
          sacc[mi][f][r] = p;
          sum += p;
        }
        l[mi][r] += sum;           // per-lane partial; red16 at epilogue
      }
    }

    // ---- P -> Ps (bf16, [q 0..63][key 0..127], chunk ^= q&7) ----
#pragma unroll
    for (int mi = 0; mi < 2; ++mi)
#pragma unroll
      for (int r = 0; r < 4; ++r) {
        const int q = wq * 32 + mi * 16 + lq * 4 + r;
#pragma unroll
        for (int f = 0; f < 4; ++f) {
          const int ch = (g * 8 + f * 2 + (lr >> 3)) ^ (q & 7);
          Ps[q * 128 + ch * 8 + (lr & 7)] = f2bf(sacc[mi][f][r]);
        }
      }

    __syncthreads();               // Ks consumed; P visible; V_j drained
    if (j < 15) stage_k(j + 1);    // overlaps PV

    // ---- O += P V over this wave's 64-key half ----
#pragma unroll
    for (int kst = 0; kst < 2; ++kst) {
      const int chA = (g * 8 + kst * 4 + lq) ^ (lr & 7);
      s16x8 pa0 = *(const s16x8*)&Ps[(wq * 32 + lr) * 128 + chA * 8];
      s16x8 pa1 = *(const s16x8*)&Ps[(wq * 32 + 16 + lr) * 128 + chA * 8];
#pragma unroll
      for (int f = 0; f < 8; ++f) {
        const int d = f * 16 + lr;
        s16x8 vf = *(const s16x8*)
            &Vs[d * 128 + (((g * 8 + kst * 4 + lq) ^ (d & 7)) << 3)];
        oacc[0][f] = __builtin_amdgcn_mfma_f32_16x16x32_bf16(pa0, vf,
                                                             oacc[0][f], 0, 0, 0);
        oacc[1][f] = __builtin_amdgcn_mfma_f32_16x16x32_bf16(pa1, vf,
                                                             oacc[1][f], 0, 0, 0);
      }
    }

    __syncthreads();               // Vs + Ps consumed; K_{j+1} drained
    if (j < 15) stage_v(j + 1);    // overlaps next S-phase
  }

  // ---- finalize l (cross-lane) then merge the two key-groups via LDS ----
  float lf[2][4];
#pragma unroll
  for (int mi = 0; mi < 2; ++mi)
#pragma unroll
    for (int r = 0; r < 4; ++r) lf[mi][r] = red_sum16(l[mi][r]);

  float* KsF = (float*)Ks;         // O1: [q 0..63][d 0..127] f32 (32 KB)
  float* mlF = (float*)Ps;         // m1,l1: [q 0..63][2]
  if (g == 1) {
#pragma unroll
    for (int mi = 0; mi < 2; ++mi)
#pragma unroll
      for (int r = 0; r < 4; ++r) {
        const int q = wq * 32 + mi * 16 + lq * 4 + r;
        if (lr == 0) { mlF[q * 2] = m[mi][r]; mlF[q * 2 + 1] = lf[mi][r]; }
#pragma unroll
        for (int f = 0; f < 8; ++f)
          KsF[q * 128 + f * 16 + lr] = oacc[mi][f][r];
      }
  }
  __syncthreads();
  if (g == 0) {
#pragma unroll
    for (int mi = 0; mi < 2; ++mi)
#pragma unroll
      for (int r = 0; r < 4; ++r) {
        const int q = wq * 32 + mi * 16 + lq * 4 + r;
        float m1 = mlF[q * 2], l1 = mlF[q * 2 + 1];
        float M = fmaxf(m[mi][r], m1);
        float w0 = exp2f(m[mi][r] - M), w1 = exp2f(m1 - M);
        float inv = 1.f / (w0 * lf[mi][r] + w1 * l1);
        w0 *= inv; w1 *= inv;
#pragma unroll
        for (int f = 0; f < 8; ++f) {
          float o = w0 * oacc[mi][f][r] + w1 * KsF[q * 128 + f * 16 + lr];
          Og[(size_t)(t * 64 + q) * HHD + h * HD_ + f * 16 + lr] = f2bf(o);
        }
      }
  }
}

// ---------------------------------------------------------------------------
// fused prep: all f32->bf16 weight casts/padding + bcat
// ---------------------------------------------------------------------------
DI void cast4(const float* __restrict__ s, u16* __restrict__ d, int v) {
  float4 f = ((const float4*)s)[v];
  unsigned lo = (unsigned)f2bf(f.x) | ((unsigned)f2bf(f.y) << 16);
  unsigned hi = (unsigned)f2bf(f.z) | ((unsigned)f2bf(f.w) << 16);
  ((uint2*)d)[v] = make_uint2(lo, hi);
}
DI void store_bf4(u16* __restrict__ d, long long i, float4 f) {
  unsigned lo = (unsigned)f2bf(f.x) | ((unsigned)f2bf(f.y) << 16);
  unsigned hi = (unsigned)f2bf(f.z) | ((unsigned)f2bf(f.w) << 16);
  *(uint2*)(d + i) = make_uint2(lo, hi);
}
static constexpr int PV_XB   = 1048576;
static constexpr int PV_WCAT = 327680;
static constexpr int PV_WQU  = 65536;
static constexpr int PV_WKU  = 262144;
static constexpr int PV_WVU  = 262144;
static constexpr int PV_WOB  = 1048576;
static constexpr int PV_BCAT = 160;
static constexpr int PV_TOT  = PV_XB + PV_WCAT + PV_WQU + PV_WKU + PV_WVU + PV_WOB + PV_BCAT;

__global__ __launch_bounds__(256) void prep(
    const float* __restrict__ x, const float* __restrict__ wqd_s,
    const float* __restrict__ wkvd_s, const float* __restrict__ wqu_s,
    const float* __restrict__ wku_s, const float* __restrict__ wvu_s,
    const float* __restrict__ wo_s, const float* __restrict__ bqd_s,
    const float* __restrict__ bkvd_s,
    u16* __restrict__ xb, u16* __restrict__ wcat, u16* __restrict__ wqu,
    u16* __restrict__ wku, u16* __restrict__ wvu, u16* __restrict__ wob,
    float* __restrict__ bcat) {
  int v = blockIdx.x * 256 + threadIdx.x;
  if (v >= PV_TOT) return;
  if (v < PV_XB) { cast4(x, xb, v); return; }
  v -= PV_XB;
  if (v < PV_WCAT) {
    int i = v * 4, n = i >> 11, k = i & 2047;
    float4 o = make_float4(0.f, 0.f, 0.f, 0.f);
    if (n < 96)        o = *(const float4*)&wqd_s[n * D_ + k];
    else if (n >= 128) o = *(const float4*)&wkvd_s[(n - 128) * D_ + k];
    store_bf4(wcat, i, o);
    return;
  }
  v -= PV_WCAT;
  if (v < PV_WQU) {
    int i = v * 4, r = i >> 7, c = i & 127;
    float4 o = (c < 96) ? *(const float4*)&wqu_s[r * 96 + c]
                        : make_float4(0.f, 0.f, 0.f, 0.f);
    store_bf4(wqu, i, o);
    return;
  }
  v -= PV_WQU;
  if (v < PV_WKU) { cast4(wku_s, wku, v); return; }
  v -= PV_WKU;
  if (v < PV_WVU) { cast4(wvu_s, wvu, v); return; }
  v -= PV_WVU;
  if (v < PV_WOB) { cast4(wo_s, wob, v); return; }
  v -= PV_WOB;
  {
    int i = v * 4;
    float4 o;
    float* po = &o.x;
#pragma unroll
    for (int jj = 0; jj < 4; ++jj) {
      int e = i + jj;
      po[jj] = (e < 96) ? bqd_s[e] : (e < 128 ? 0.f : bkvd_s[e - 128]);
    }
    *(float4*)&bcat[i] = o;
  }
}

// ---------------------------------------------------------------------------
extern "C" void kernel_launch(void* const* d_in, const int* in_sizes, int n_in,
                              void* d_out, int out_size, void* d_ws, size_t ws_size,
                              hipStream_t stream) {
  (void)in_sizes; (void)n_in; (void)out_size; (void)ws_size;
  const float* x        = (const float*)d_in[0];
  const float* rc       = (const float*)d_in[1];
  const float* rs       = (const float*)d_in[2];
  const float* wq_down  = (const float*)d_in[3];
  const float* bq_down  = (const float*)d_in[4];
  const float* wq_up    = (const float*)d_in[5];
  const float* bq_up    = (const float*)d_in[6];
  const float* wkv_down = (const float*)d_in[7];
  const float* bkv_down = (const float*)d_in[8];
  const float* wk_up    = (const float*)d_in[9];
  const float* bk_up    = (const float*)d_in[10];
  const float* wv_up    = (const float*)d_in[11];
  const float* bv_up    = (const float*)d_in[12];
  const float* wo       = (const float*)d_in[13];
  const float* bo       = (const float*)d_in[14];
  float* out = (float*)d_out;

  char* ws = (char*)d_ws;
  size_t off = 0;
  auto alloc = [&](size_t bytes) -> void* {
    off = (off + 255) & ~(size_t)255;
    void* p = ws + off;
    off += bytes;
    return p;
  };

  u16* xb      = (u16*)alloc((size_t)S_ * D_ * 2);
  u16* wcat    = (u16*)alloc((size_t)NCAT * D_ * 2);
  float* bcat  = (float*)alloc(NCAT * 4);
  u16* wqu     = (u16*)alloc((size_t)HHD * CQP * 2);
  u16* wku     = (u16*)alloc((size_t)HHD * CKV_ * 2);
  u16* wvu     = (u16*)alloc((size_t)HHD * CKV_ * 2);
  u16* wob     = (u16*)alloc((size_t)D_ * HHD * 2);
  u16* ccat    = (u16*)alloc((size_t)S_ * NCAT * 2);
  u16* qb      = (u16*)alloc((size_t)S_ * HHD * 2);
  u16* kb      = (u16*)alloc((size_t)S_ * HHD * 2);
  u16* vT      = (u16*)alloc((size_t)HHD * S_ * 2);   // [h*128+d][s]
  u16* attnb   = (u16*)alloc((size_t)S_ * HHD * 2);
  // pool shared by pcat (21 MB, early) and pout (33.5 MB, late)
  float* pool  = (float*)alloc((size_t)2 * S_ * D_ * 4);
  float* pcat  = pool;
  float* pout  = pool;

  // ---- fused prep ----
  prep<<<(PV_TOT + 255) / 256, 256, 0, stream>>>(
      x, wq_down, wkv_down, wq_up, wk_up, wv_up, wo, bq_down, bkv_down,
      xb, wcat, wqu, wku, wvu, wob, bcat);

  // ---- fused c_q|c_kv projection, split-K x4 ----
  gemm_bt<float, 0, 0, 64><<<dim3(NCAT / 64, 16, 4), 256, 0, stream>>>(
      xb, wcat, pcat, nullptr, nullptr, 512, D_, D_, NCAT,
      512, 512, (long long)S_ * NCAT);
  combine_z<u16><<<(S_ * NCAT / 4 + 255) / 256, 256, 0, stream>>>(
      pcat, (long long)S_ * NCAT, 4, bcat, ccat, NCAT, S_ * NCAT / 4);

  // ---- up-projections with fused RoPE for q/k (3 blocks/CU) ----
  up3<<<dim3(16, 16, 3), 256, 0, stream>>>(
      ccat, wqu, wku, wvu, bq_up, bk_up, bv_up, rc, rs, qb, kb, vT);

  // ---- fused flash attention (q-tile 64, 512 blocks = 2/CU) ----
  flash_attn<<<dim3(H_, S_ / 64, 1), 256, 0, stream>>>(qb, kb, vT, attnb);

  // ---- output projection, split-K x2, f32 combine w/ bias ----
  gemm_bt<float, 0, 0, 128><<<dim3(16, 16, 2), 256, 0, stream>>>(
      attnb, wob, pout, nullptr, nullptr, 1024, HHD, HHD, D_,
      1024, 1024, (long long)S_ * D_);
  combine_z<float><<<(S_ * D_ / 4 + 255) / 256, 256, 0, stream>>>(
      pout, (long long)S_ * D_, 2, bo, out, D_, S_ * D_ / 4);
}